// Round 5
// baseline (18630.545 us; speedup 1.0000x reference)
//
#include <hip/hip_runtime.h>

// ---------------------------------------------------------------------------
// Adaptive-attention LSTM decoder (B=128, P=49, D=E=A=512, V=10000, T=50).
//  * Persistent scan: 64 co-resident blocks, 6 col-parallel phases/step.
//  * R=1 weight ownership: every weight byte is read by exactly ONE persistent
//    block -> stays L2-resident on that block's XCD (no mapping assumptions).
//    Aggregate hot set: 12.5 MB weights + 12.8 MB SPB/VAB < 32 MB L2.
//  * A-matrices (128x512 bf16) broadcast via coherent (sc0 sc1) bulk stages,
//    K-chunked + double-buffered in LDS, XOR-swizzled.
//  * g2p partials park in REGISTERS across the attention phase (same block
//    computes g2p and LSTM2 with identical lane mapping).
//  * Precompute: P1/Ps input-side gates, visual_att (bf16); final: fc GEMM.
// ---------------------------------------------------------------------------

typedef unsigned short u16;
typedef unsigned long long ull;
typedef short bf16x8 __attribute__((ext_vector_type(8)));
typedef float f32x4 __attribute__((ext_vector_type(4)));

#define MFMA16(a, b, c) __builtin_amdgcn_mfma_f32_16x16x32_bf16(a, b, c, 0, 0, 0)
#define NBLK 64

__device__ __forceinline__ u16 f2bf(float f) {
    union { float f; unsigned u; } v; v.f = f;
    return (u16)((v.u + 0x7fffu + ((v.u >> 16) & 1u)) >> 16);
}
__device__ __forceinline__ float bf2f(u16 h) {
    union { unsigned u; float f; } v; v.u = ((unsigned)h) << 16; return v.f;
}
__device__ __forceinline__ float sigm(float x) {
    x = fminf(fmaxf(x, -30.f), 30.f);
    return 1.f / (1.f + __expf(-x));
}
__device__ __forceinline__ float tanh_(float x) {
    x = fminf(fmaxf(x, -15.f), 15.f);
    float e = __expf(2.f * x);
    return (e - 1.f) / (e + 1.f);
}

// ---- agent-scope (cross-XCD coherent, cache-bypassing) accessors ----
__device__ __forceinline__ ull ldq(const u16* p) {
    return __hip_atomic_load((const ull*)p, __ATOMIC_RELAXED, __HIP_MEMORY_SCOPE_AGENT);
}
__device__ __forceinline__ float ld32(const float* p) {
    return __hip_atomic_load(p, __ATOMIC_RELAXED, __HIP_MEMORY_SCOPE_AGENT);
}
__device__ __forceinline__ unsigned ld32u(const u16* p) {
    return __hip_atomic_load((const unsigned*)p, __ATOMIC_RELAXED, __HIP_MEMORY_SCOPE_AGENT);
}
__device__ __forceinline__ void st32(float* p, float v) {
    __hip_atomic_store(p, v, __ATOMIC_RELAXED, __HIP_MEMORY_SCOPE_AGENT);
}
__device__ __forceinline__ void st32u(u16* p, unsigned v) {
    __hip_atomic_store((unsigned*)p, v, __ATOMIC_RELAXED, __HIP_MEMORY_SCOPE_AGENT);
}
__device__ __forceinline__ void st16(u16* p, u16 v) {
    asm volatile("global_store_short %0, %1, off sc0 sc1" :: "v"(p), "v"((unsigned)v) : "memory");
}

// Fence-free grid barrier: drain own bypass stores, count arrivals.
__device__ __forceinline__ void grid_barrier(int* bar, int idx) {
    asm volatile("s_waitcnt vmcnt(0)" ::: "memory");
    __syncthreads();
    if (threadIdx.x == 0) {
        __hip_atomic_fetch_add(&bar[idx], 1, __ATOMIC_RELAXED, __HIP_MEMORY_SCOPE_AGENT);
        while (__hip_atomic_load(&bar[idx], __ATOMIC_RELAXED, __HIP_MEMORY_SCOPE_AGENT) < NBLK)
            __builtin_amdgcn_s_sleep(1);
    }
    __syncthreads();
    asm volatile("" ::: "memory");
}

// ---------------------------------------------------------------------------
// Column-parallel GEMM: C[128 x NT*16] += A[128 x K] @ W[wrow0.. , K]^T.
// A = [A0 | A1] (each [128][512] bf16) split at `asplit`, loaded coherently,
// staged in 128-col chunks (32 KB) double-buffered + swizzled in LDS.
// W: cached loads (L2-resident slice). All 4 waves: wave w -> rows w*32..+32.
template<int NT>
__device__ __forceinline__ void gemmCP(const u16* A0, const u16* A1, int asplit, int K,
                                       const u16* __restrict__ W, int ldw, int wrow0,
                                       u16* lds, f32x4 acc[2][NT]) {
    const int tid = threadIdx.x;
    const int w = tid >> 6, lane = tid & 63, r = lane & 15, lg = lane >> 4;
    const int m_base = w * 32;
    const int srow = tid >> 1, scol0 = (tid & 1) * 64;
    const int nch = K >> 7;
    for (int kc = 0; kc < nch; ++kc) {
        u16* buf = lds + (kc & 1) * 16384;
        int kbase = kc << 7;
        ull t0[8], t1[8];
#pragma unroll
        for (int i = 0; i < 8; ++i) {
            int col = kbase + scol0 + i * 8;
            const u16* src = (col < asplit) ? (A0 + (size_t)srow * 512 + col)
                                            : (A1 + (size_t)srow * 512 + (col - asplit));
            t0[i] = ldq(src);
            t1[i] = ldq(src + 4);
        }
        __builtin_amdgcn_sched_barrier(0);
#pragma unroll
        for (int i = 0; i < 8; ++i) {
            int c16 = (scol0 >> 3) + i;
            int sw = c16 ^ (srow & 7);
            ull* dst = (ull*)(buf + srow * 128 + sw * 8);
            dst[0] = t0[i];
            dst[1] = t1[i];
        }
        __syncthreads();   // one sync per chunk; dbuf makes this sufficient
#pragma unroll
        for (int k0 = 0; k0 < 128; k0 += 32) {
            int kk = k0 + lg * 8;
            int c16 = kk >> 3;
            int ra0 = m_base + r, ra1 = m_base + 16 + r;
            bf16x8 a0 = *(const bf16x8*)(buf + ra0 * 128 + ((c16 ^ (ra0 & 7)) << 3));
            bf16x8 a1 = *(const bf16x8*)(buf + ra1 * 128 + ((c16 ^ (ra1 & 7)) << 3));
#pragma unroll
            for (int j = 0; j < NT; ++j) {
                bf16x8 wf = *(const bf16x8*)(W + (size_t)(wrow0 + j * 16 + r) * ldw + kbase + kk);
                acc[0][j] = MFMA16(a0, wf, acc[0][j]);
                acc[1][j] = MFMA16(a1, wf, acc[1][j]);
            }
        }
    }
    __syncthreads();
}

// Plain-global-A gemm (pre/post kernels only).
__device__ __forceinline__ void gemm_2x4(const u16* __restrict__ A0, const u16* __restrict__ A1,
                                         int asplit, int lda0, int lda1,
                                         const u16* __restrict__ W, int ldw, int K,
                                         int m_base, int n_base, int nt, f32x4 acc[2][4]) {
    const int lane = threadIdx.x & 63, r = lane & 15, lg = lane >> 4;
    for (int k0 = 0; k0 < K; k0 += 32) {
        int kk = k0 + lg * 8;
        const u16* Ab; int ka, lda;
        if (k0 < asplit) { Ab = A0; ka = kk; lda = lda0; }
        else             { Ab = A1; ka = kk - asplit; lda = lda1; }
        bf16x8 a0 = *(const bf16x8*)(Ab + (size_t)(m_base + r) * lda + ka);
        bf16x8 a1 = *(const bf16x8*)(Ab + (size_t)(m_base + 16 + r) * lda + ka);
#pragma unroll
        for (int j = 0; j < 4; ++j) {
            if (j < nt) {
                bf16x8 wf = *(const bf16x8*)(W + (size_t)(n_base + j * 16 + r) * ldw + kk);
                acc[0][j] = MFMA16(a0, wf, acc[0][j]);
                acc[1][j] = MFMA16(a1, wf, acc[1][j]);
            }
        }
    }
}

// ---------------- one-time conversion / packing kernels ----------------

__global__ __launch_bounds__(256) void k_cvt8(
    const float* __restrict__ s0, const float* __restrict__ s1, const float* __restrict__ s2,
    const float* __restrict__ s3, const float* __restrict__ s4, const float* __restrict__ s5,
    const float* __restrict__ s6, const float* __restrict__ s7,
    u16* __restrict__ d0, u16* __restrict__ d1, u16* __restrict__ d2, u16* __restrict__ d3,
    u16* __restrict__ d4, u16* __restrict__ d5, u16* __restrict__ d6, u16* __restrict__ d7) {
    int i = blockIdx.x * 256 + threadIdx.x;
    const int S = 262144;
    if (i < 6 * S) {
        int seg = i >> 18, off = i & (S - 1);
        const float* s = seg == 0 ? s0 : seg == 1 ? s1 : seg == 2 ? s2 : seg == 3 ? s3 : seg == 4 ? s4 : s5;
        u16* d = seg == 0 ? d0 : seg == 1 ? d1 : seg == 2 ? d2 : seg == 3 ? d3 : seg == 4 ? d4 : d5;
        d[off] = f2bf(s[off]);
    } else if (i < 6 * S + 5120000) {
        int off = i - 6 * S;
        d6[off] = f2bf(s6[off]);
    } else {
        int off = i - 6 * S - 5120000;
        if (off < 3211264) d7[off] = f2bf(s7[off]);
    }
}

// input-side weight slices for the batched precompute
__global__ __launch_bounds__(256) void k_packX(const float* __restrict__ w_ih1,
                                               const float* __restrict__ s_wx,
                                               u16* __restrict__ W1X, u16* __restrict__ WSX) {
    int i = blockIdx.x * 256 + threadIdx.x;
    if (i < 2097152) {
        W1X[i] = f2bf(w_ih1[(size_t)(i >> 10) * 1536 + 512 + (i & 1023)]);
    } else if (i < 2621440) {
        int i2 = i - 2097152;
        WSX[i2] = f2bf(s_wx[(size_t)(i2 >> 10) * 1536 + 512 + (i2 & 1023)]);
    }
}

// Column-parallel scan weight layouts (colg = owning block's slice):
//  W1S [2560][1024]: row' = colg*160 + g*32 + dl  (g in {i,f,g,o,sent}), d = colg*32+dl
//                    K = [h2 (w_ih1[:, :512] / s_wx[:, :512]) | h1 (w_hh1 / s_wh)]
//  W2H [2048][1024]: row' = colg*128 + g*32 + dl; K = [h1n (w_ih2[:,512:]) | h2 (w_hh2)]
//  W2A [2048][ 512]: row' = colg*128 + g*32 + dl; K = att (w_ih2[:, :512])
__global__ __launch_bounds__(256) void k_packS(
    const float* __restrict__ w_ih1, const float* __restrict__ w_hh1,
    const float* __restrict__ s_wx, const float* __restrict__ s_wh,
    const float* __restrict__ w_ih2, const float* __restrict__ w_hh2,
    u16* __restrict__ W1S, u16* __restrict__ W2H, u16* __restrict__ W2A) {
    int i = blockIdx.x * 256 + threadIdx.x;
    if (i < 2621440) {
        int rp = i >> 10, k = i & 1023;
        int colg = rp / 160, rem = rp - colg * 160, g = rem >> 5, dl = rem & 31;
        int d = colg * 32 + dl;
        float v;
        if (g < 4) v = (k < 512) ? w_ih1[(size_t)(g * 512 + d) * 1536 + k]
                                 : w_hh1[(size_t)(g * 512 + d) * 512 + (k - 512)];
        else       v = (k < 512) ? s_wx[(size_t)d * 1536 + k]
                                 : s_wh[(size_t)d * 512 + (k - 512)];
        W1S[i] = f2bf(v);
    } else if (i < 2621440 + 2097152) {
        int i2 = i - 2621440;
        int rp = i2 >> 10, k = i2 & 1023;
        int colg = rp >> 7, rem = rp & 127, g = rem >> 5, dl = rem & 31;
        int d = colg * 32 + dl;
        float v = (k < 512) ? w_ih2[(size_t)(g * 512 + d) * 1024 + 512 + k]
                            : w_hh2[(size_t)(g * 512 + d) * 512 + (k - 512)];
        W2H[i2] = f2bf(v);
    } else if (i < 2621440 + 2097152 + 1048576) {
        int i3 = i - 2621440 - 2097152;
        int rp = i3 >> 9, k = i3 & 511;
        int colg = rp >> 7, rem = rp & 127, g = rem >> 5, dl = rem & 31;
        int d = colg * 32 + dl;
        W2A[i3] = f2bf(w_ih2[(size_t)(g * 512 + d) * 1024 + k]);
    }
}

// xw[t][b][k] : k<512 -> emb[cap[b][t]][k], else global_image[b][k-512]
__global__ __launch_bounds__(256) void k_xw(const float* __restrict__ emb, const float* __restrict__ gimg,
                                            const int* __restrict__ cap, u16* __restrict__ XW, int total) {
    int i = blockIdx.x * 256 + threadIdx.x;
    if (i >= total) return;
    int t = i >> 17;
    int rem = i & ((1 << 17) - 1);
    int b = rem >> 10, k = rem & 1023;
    float v = (k < 512) ? emb[(size_t)cap[b * 50 + t] * 512 + k] : gimg[b * 512 + (k - 512)];
    XW[i] = f2bf(v);
}

// ---------------- batched precompute GEMMs ----------------

__global__ __launch_bounds__(256) void k_p1ps(const u16* __restrict__ XW, const u16* __restrict__ W1X,
                                              const u16* __restrict__ WSX,
                                              const float* __restrict__ b_ih1, const float* __restrict__ b_hh1,
                                              const float* __restrict__ s_bx, const float* __restrict__ s_bh,
                                              float* __restrict__ P1, float* __restrict__ PS) {
    int bid = blockIdx.x;
    int ng = bid % 40, mg = bid / 40;
    int w = threadIdx.x >> 6, lane = threadIdx.x & 63, r = lane & 15, lg = lane >> 4;
    int m_base = mg * 128 + w * 32;
    f32x4 acc[2][4] = {};
    if (ng < 32) {
        int n_base = ng * 64;
        gemm_2x4(XW, XW, 1 << 28, 1024, 1024, W1X, 1024, 1024, m_base, n_base, 4, acc);
#pragma unroll
        for (int mt = 0; mt < 2; ++mt)
#pragma unroll
            for (int j = 0; j < 4; ++j)
#pragma unroll
                for (int reg = 0; reg < 4; ++reg) {
                    int row = m_base + mt * 16 + lg * 4 + reg;
                    int col = n_base + j * 16 + r;
                    P1[(size_t)row * 2048 + col] = acc[mt][j][reg] + b_ih1[col] + b_hh1[col];
                }
    } else {
        int n_base = (ng - 32) * 64;
        gemm_2x4(XW, XW, 1 << 28, 1024, 1024, WSX, 1024, 1024, m_base, n_base, 4, acc);
#pragma unroll
        for (int mt = 0; mt < 2; ++mt)
#pragma unroll
            for (int j = 0; j < 4; ++j)
#pragma unroll
                for (int reg = 0; reg < 4; ++reg) {
                    int row = m_base + mt * 16 + lg * 4 + reg;
                    int col = n_base + j * 16 + r;
                    PS[(size_t)row * 512 + col] = acc[mt][j][reg] + s_bx[col] + s_bh[col];
                }
    }
}

__global__ __launch_bounds__(256) void k_va(const u16* __restrict__ SPB, const u16* __restrict__ WVB,
                                            const float* __restrict__ wv_b, u16* __restrict__ VAB) {
    int bid = blockIdx.x;
    int ng = bid % 8, mg = bid / 8;
    int w = threadIdx.x >> 6, lane = threadIdx.x & 63, r = lane & 15, lg = lane >> 4;
    int m_base = mg * 128 + w * 32;
    int n_base = ng * 64;
    f32x4 acc[2][4] = {};
    gemm_2x4(SPB, SPB, 1 << 28, 512, 512, WVB, 512, 512, m_base, n_base, 4, acc);
#pragma unroll
    for (int mt = 0; mt < 2; ++mt)
#pragma unroll
        for (int j = 0; j < 4; ++j)
#pragma unroll
            for (int reg = 0; reg < 4; ++reg) {
                int row = m_base + mt * 16 + lg * 4 + reg;
                int col = n_base + j * 16 + r;
                VAB[(size_t)row * 512 + col] = f2bf(acc[mt][j][reg] + wv_b[col]);
            }
}

// ---------------- persistent scan phase bodies ----------------

// PhA: LSTM1 + sentinel. Blocks 0..15: colg = bid, cols = 5 gates x 32 d.
__device__ __forceinline__ void p_lstm1(int colg, const u16* H2BF, const u16* H1C,
                                        const u16* __restrict__ W1S,
                                        const float* __restrict__ P1, const float* __restrict__ PS,
                                        float* M1, u16* H1N, u16* STBF, int t, u16* lds) {
    f32x4 acc[2][10] = {};
    gemmCP<10>(H2BF, H1C, 512, 1024, W1S, 1024, colg * 160, lds, acc);
    int tid = threadIdx.x;
    int w = tid >> 6, lane = tid & 63, r = lane & 15, lg = lane >> 4;
#pragma unroll
    for (int mt = 0; mt < 2; ++mt)
#pragma unroll
        for (int dh = 0; dh < 2; ++dh)
#pragma unroll
            for (int reg = 0; reg < 4; ++reg) {
                int row = w * 32 + mt * 16 + lg * 4 + reg;
                int d = colg * 32 + dh * 16 + r;
                const float* p1r = P1 + ((size_t)t * 128 + row) * 2048;
                float gi = acc[mt][0 + dh][reg] + p1r[d];
                float gf = acc[mt][2 + dh][reg] + p1r[512 + d];
                float gg = acc[mt][4 + dh][reg] + p1r[1024 + d];
                float go = acc[mt][6 + dh][reg] + p1r[1536 + d];
                float gs = acc[mt][8 + dh][reg] + PS[((size_t)t * 128 + row) * 512 + d];
                int pidx = (colg * 16 + (mt * 2 + dh) * 4 + reg) * 256 + tid;
                float m1n = sigm(gf) * M1[pidx] + sigm(gi) * tanh_(gg);
                M1[pidx] = m1n;
                float tm = tanh_(m1n);
                st16(H1N + row * 512 + d, f2bf(sigm(go) * tm));
                st16(STBF + row * 512 + d, f2bf(sigm(gs) * tm));
            }
}

// Small col-parallel GEMM (N-slice = 32 cols) with activation/output variants.
// ACT: 0 relu->bf16 OB; 1 tanh->f32 OF + bf16 OB; 2 none->f32 OF; 3 tanh->bf16 OB.
template<int ACT>
__device__ __forceinline__ void ph_small(int colg, const u16* A,
                                         const u16* __restrict__ W, const float* __restrict__ bias,
                                         u16* OB, float* OF, u16* lds) {
    f32x4 acc[2][2] = {};
    gemmCP<2>(A, A, 1 << 28, 512, W, 512, colg * 32, lds, acc);
    int w = threadIdx.x >> 6, lane = threadIdx.x & 63, r = lane & 15, lg = lane >> 4;
#pragma unroll
    for (int mt = 0; mt < 2; ++mt)
#pragma unroll
        for (int j = 0; j < 2; ++j)
#pragma unroll
            for (int reg = 0; reg < 4; ++reg) {
                int row = w * 32 + mt * 16 + lg * 4 + reg;
                int col = colg * 32 + j * 16 + r;
                float v = acc[mt][j][reg] + bias[col];
                if (ACT == 0) { v = fmaxf(v, 0.f); st16(OB + row * 512 + col, f2bf(v)); }
                if (ACT == 1) { v = tanh_(v); st32(OF + row * 512 + col, v);
                                st16(OB + row * 512 + col, f2bf(v)); }
                if (ACT == 2) { st32(OF + row * 512 + col, v); }
                if (ACT == 3) { v = tanh_(v); st16(OB + row * 512 + col, f2bf(v)); }
            }
}

// PhD: adaptive attention; thread-halves handle batch rows bid and bid+64.
struct AttSm { float whwL[512]; float hidL[2][512]; float zbuf[2][64]; float albuf[2][64]; };

__device__ __forceinline__ void p3_attn(int bid, const u16* __restrict__ VAB, const float* SEN,
                                        const float* HID, const float* __restrict__ whw,
                                        const float* __restrict__ whb, const u16* __restrict__ SPB,
                                        const u16* S2BF, const float* HTF, u16* CHHBF, AttSm* A) {
    int tid = threadIdx.x;
    int half = tid >> 7, th = tid & 127;
    int b = bid + half * 64;
    for (int i = tid; i < 512; i += 256) A->whwL[i] = whw[i];
    for (int i = th; i < 512; i += 128) A->hidL[half][i] = ld32(HID + (size_t)b * 512 + i);
    __syncthreads();
    int w2 = th >> 6, lane = tid & 63;
    for (int p = w2; p < 50; p += 2) {
        float part = 0.f;
        if (p < 49) {
            const u16* src = VAB + ((size_t)b * 49 + p) * 512;
#pragma unroll
            for (int it = 0; it < 8; ++it) {
                int a = lane + it * 64;
                part += tanh_(bf2f(src[a]) + A->hidL[half][a]) * A->whwL[a];
            }
        } else {
#pragma unroll
            for (int it = 0; it < 8; ++it) {
                int a = lane + it * 64;
                part += tanh_(ld32(SEN + (size_t)b * 512 + a) + A->hidL[half][a]) * A->whwL[a];
            }
        }
#pragma unroll
        for (int o = 32; o; o >>= 1) part += __shfl_xor(part, o, 64);
        if (lane == 0) A->zbuf[half][p] = part + whb[0];
    }
    __syncthreads();
    if (th < 64) {
        float v = (lane < 50) ? A->zbuf[half][lane] : -1e30f;
        float mx = v;
#pragma unroll
        for (int o = 32; o; o >>= 1) mx = fmaxf(mx, __shfl_xor(mx, o, 64));
        float e = (lane < 50) ? __expf(v - mx) : 0.f;
        float s = e;
#pragma unroll
        for (int o = 32; o; o >>= 1) s += __shfl_xor(s, o, 64);
        if (lane < 50) A->albuf[half][lane] = e / s;
    }
    __syncthreads();
    float a49 = A->albuf[half][49];
    int d0 = th * 4;
    unsigned s2a = ld32u(S2BF + (size_t)b * 512 + d0);
    unsigned s2b = ld32u(S2BF + (size_t)b * 512 + d0 + 2);
    float acc0 = a49 * bf2f((u16)s2a), acc1 = a49 * bf2f((u16)(s2a >> 16));
    float acc2 = a49 * bf2f((u16)s2b), acc3 = a49 * bf2f((u16)(s2b >> 16));
    for (int p = 0; p < 49; ++p) {
        const u16* sf = SPB + ((size_t)b * 49 + p) * 512 + d0;
        unsigned q0 = *(const unsigned*)sf, q1 = *(const unsigned*)(sf + 2);
        float al = A->albuf[half][p];
        acc0 += al * bf2f((u16)q0); acc1 += al * bf2f((u16)(q0 >> 16));
        acc2 += al * bf2f((u16)q1); acc3 += al * bf2f((u16)(q1 >> 16));
    }
    acc0 += ld32(HTF + (size_t)b * 512 + d0);
    acc1 += ld32(HTF + (size_t)b * 512 + d0 + 1);
    acc2 += ld32(HTF + (size_t)b * 512 + d0 + 2);
    acc3 += ld32(HTF + (size_t)b * 512 + d0 + 3);
    st32u(CHHBF + (size_t)b * 512 + d0, (unsigned)f2bf(acc0) | ((unsigned)f2bf(acc1) << 16));
    st32u(CHHBF + (size_t)b * 512 + d0 + 2, (unsigned)f2bf(acc2) | ((unsigned)f2bf(acc3) << 16));
}

// PhE2: LSTM2. g2acc holds the hidden-side partials parked in registers.
__device__ __forceinline__ void p_lstm2(int colg, const u16* ATTBF,
                                        const u16* __restrict__ W2A,
                                        const float* __restrict__ b_ih2, const float* __restrict__ b_hh2,
                                        float* M2, u16* H2BF, u16* H2ALL, int t, u16* lds,
                                        f32x4 g2acc[2][8]) {
    gemmCP<8>(ATTBF, ATTBF, 1 << 28, 512, W2A, 512, colg * 128, lds, g2acc);
    int tid = threadIdx.x;
    int w = tid >> 6, lane = tid & 63, r = lane & 15, lg = lane >> 4;
#pragma unroll
    for (int mt = 0; mt < 2; ++mt)
#pragma unroll
        for (int dh = 0; dh < 2; ++dh)
#pragma unroll
            for (int reg = 0; reg < 4; ++reg) {
                int row = w * 32 + mt * 16 + lg * 4 + reg;
                int d = colg * 32 + dh * 16 + r;
                float gi = g2acc[mt][0 + dh][reg] + b_ih2[d]        + b_hh2[d];
                float gf = g2acc[mt][2 + dh][reg] + b_ih2[512 + d]  + b_hh2[512 + d];
                float gg = g2acc[mt][4 + dh][reg] + b_ih2[1024 + d] + b_hh2[1024 + d];
                float go = g2acc[mt][6 + dh][reg] + b_ih2[1536 + d] + b_hh2[1536 + d];
                int pidx = (colg * 16 + (mt * 2 + dh) * 4 + reg) * 256 + tid;
                float m2n = sigm(gf) * M2[pidx] + sigm(gi) * tanh_(gg);
                M2[pidx] = m2n;
                u16 hb = f2bf(sigm(go) * tanh_(m2n));
                st16(H2BF + row * 512 + d, hb);
                st16(H2ALL + ((size_t)t * 128 + row) * 512 + d, hb);
            }
}

__global__ __launch_bounds__(256) void k_scan(
    const u16* __restrict__ W1S, const u16* __restrict__ W2H, const u16* __restrict__ W2A,
    const u16* __restrict__ AFFS, const u16* __restrict__ AFFH,
    const u16* __restrict__ WSB, const u16* __restrict__ WGB, const u16* __restrict__ WPB,
    const float* __restrict__ P1, const float* __restrict__ PS,
    const u16* __restrict__ VAB, const u16* __restrict__ SPB,
    const float* __restrict__ b_ih2, const float* __restrict__ b_hh2,
    const float* __restrict__ affs_b, const float* __restrict__ affh_b,
    const float* __restrict__ wg_b, const float* __restrict__ ws_b, const float* __restrict__ wp_b,
    const float* __restrict__ whw, const float* __restrict__ whb,
    u16* H1A, u16* H1B, u16* H2BF, u16* STBF, u16* S2BF, u16* HTBF, u16* CHHBF, u16* ATTBF,
    float* M1, float* M2, float* HTF, float* HID, float* SEN,
    u16* H2ALL, int* bar) {
    union SmemU {
        ull stage[8192];   // 64 KiB stage double-buffer
        AttSm att;
    };
    __shared__ SmemU sm;
    u16* lds = (u16*)&sm;
    int bid = blockIdx.x;
    int bi = 0;
    for (int t = 0; t < 49; ++t) {
        const u16* h1c = (t & 1) ? H1B : H1A;
        u16* h1n = (t & 1) ? H1A : H1B;
        // PhA: LSTM1 + sentinel (blocks 0..15)
        if (bid < 16) p_lstm1(bid, H2BF, h1c, W1S, P1, PS, M1, h1n, STBF, t, lds);
        grid_barrier(bar, bi++);
        // PhB: g2p (0..15, partials stay in registers), s2 (16..31), ht (32..47)
        f32x4 g2acc[2][8] = {};
        if (bid < 16)      gemmCP<8>(h1n, H2BF, 512, 1024, W2H, 1024, bid * 128, lds, g2acc);
        else if (bid < 32) ph_small<0>(bid - 16, STBF, AFFS, affs_b, S2BF, (float*)0, lds);
        else if (bid < 48) ph_small<1>(bid - 32, h1n, AFFH, affh_b, HTBF, HTF, lds);
        grid_barrier(bar, bi++);
        // PhC: sen (16..31), hid (32..47)
        if (bid >= 16 && bid < 32)      ph_small<2>(bid - 16, S2BF, WSB, ws_b, (u16*)0, SEN, lds);
        else if (bid >= 32 && bid < 48) ph_small<2>(bid - 32, HTBF, WGB, wg_b, (u16*)0, HID, lds);
        grid_barrier(bar, bi++);
        // PhD: attention (all 64 blocks, 2 batch rows each)
        p3_attn(bid, VAB, SEN, HID, whw, whb, SPB, S2BF, HTF, CHHBF, &sm.att);
        grid_barrier(bar, bi++);
        // PhE1: att_out = tanh(chh @ wp^T + b) (blocks 16..31)
        if (bid >= 16 && bid < 32) ph_small<3>(bid - 16, CHHBF, WPB, wp_b, ATTBF, (float*)0, lds);
        grid_barrier(bar, bi++);
        // PhE2: LSTM2 (blocks 0..15, consumes register-parked g2acc)
        if (bid < 16) p_lstm2(bid, ATTBF, W2A, b_ih2, b_hh2, M2, H2BF, H2ALL, t, lds, g2acc);
        if (t < 48) grid_barrier(bar, bi++);
    }
}

// Final: preds[b][t][v] = H2all[t*128+b] @ fc_w^T + fc_b
__global__ __launch_bounds__(256) void k_fc(const u16* __restrict__ H2ALL, const u16* __restrict__ FCB,
                                            const float* __restrict__ fc_b, float* __restrict__ out) {
    int bid = blockIdx.x;
    int ng = bid % 157, mg = bid / 157;
    int w = threadIdx.x >> 6, lane = threadIdx.x & 63, r = lane & 15, lg = lane >> 4;
    int m_base = mg * 128 + w * 32;
    int n_base = ng * 64;
    int nt = (10000 - n_base) / 16; if (nt > 4) nt = 4;
    f32x4 acc[2][4] = {};
    gemm_2x4(H2ALL, H2ALL, 1 << 28, 512, 512, FCB, 512, 512, m_base, n_base, nt, acc);
#pragma unroll
    for (int mt = 0; mt < 2; ++mt)
#pragma unroll
        for (int j = 0; j < 4; ++j) {
            if (j < nt) {
#pragma unroll
                for (int reg = 0; reg < 4; ++reg) {
                    int row = m_base + mt * 16 + lg * 4 + reg;
                    int col = n_base + j * 16 + r;
                    int t = row >> 7, b = row & 127;
                    out[((size_t)b * 49 + t) * 10000 + col] = acc[mt][j][reg] + fc_b[col];
                }
            }
        }
}

// ---------------------------------------------------------------------------

extern "C" void kernel_launch(void* const* d_in, const int* in_sizes, int n_in,
                              void* d_out, int out_size, void* d_ws, size_t ws_size,
                              hipStream_t stream) {
    (void)in_sizes; (void)n_in; (void)out_size; (void)ws_size;

    const float* SF      = (const float*)d_in[0];
    const float* GIMG    = (const float*)d_in[1];
    const int*   CAP     = (const int*)d_in[2];
    const float* EMB     = (const float*)d_in[4];
    const float* w_ih1   = (const float*)d_in[5];
    const float* w_hh1   = (const float*)d_in[6];
    const float* b_ih1   = (const float*)d_in[7];
    const float* b_hh1   = (const float*)d_in[8];
    const float* s_wx    = (const float*)d_in[9];
    const float* s_bx    = (const float*)d_in[10];
    const float* s_wh    = (const float*)d_in[11];
    const float* s_bh    = (const float*)d_in[12];
    const float* w_ih2   = (const float*)d_in[13];
    const float* w_hh2   = (const float*)d_in[14];
    const float* b_ih2   = (const float*)d_in[15];
    const float* b_hh2   = (const float*)d_in[16];
    const float* aff_s_w = (const float*)d_in[17];
    const float* aff_s_b = (const float*)d_in[18];
    const float* aff_h_w = (const float*)d_in[19];
    const float* aff_h_b = (const float*)d_in[20];
    const float* ws_w    = (const float*)d_in[21];
    const float* ws_b    = (const float*)d_in[22];
    const float* wg_w    = (const float*)d_in[23];
    const float* wg_b    = (const float*)d_in[24];
    const float* wv_w    = (const float*)d_in[25];
    const float* wv_b    = (const float*)d_in[26];
    const float* wh_w    = (const float*)d_in[27];
    const float* wh_b    = (const float*)d_in[28];
    const float* wp_w    = (const float*)d_in[29];
    const float* wp_b    = (const float*)d_in[30];
    const float* fc_w    = (const float*)d_in[31];
    const float* fc_b    = (const float*)d_in[32];

    float* out = (float*)d_out;

    // fp32 scratch in d_out (fc overwrites all of d_out at the end):
    float* P1 = out;                       // 49*128*2048 = 12,845,056 floats
    float* PS = out + 12845056;            //  3,211,264 floats
    u16*  XWB = (u16*)(out + 17000000);    //  6,422,528 u16 (consumed before scan)

    char* ws = (char*)d_ws;
    size_t off = 0;
    auto alloc = [&](size_t elts, size_t esz) -> void* {
        void* p = ws + off;
        off += (elts * esz + 255) & ~(size_t)255;
        return p;
    };
    u16* W1S   = (u16*)alloc(2621440, 2);
    u16* W2H   = (u16*)alloc(2097152, 2);
    u16* W2A   = (u16*)alloc(1048576, 2);
    u16* W1X   = (u16*)alloc(2097152, 2);
    u16* WSX   = (u16*)alloc(524288, 2);
    u16* AFFS  = (u16*)alloc(262144, 2);
    u16* AFFH  = (u16*)alloc(262144, 2);
    u16* WSB   = (u16*)alloc(262144, 2);
    u16* WGB   = (u16*)alloc(262144, 2);
    u16* WVB   = (u16*)alloc(262144, 2);
    u16* WPB   = (u16*)alloc(262144, 2);
    u16* FCB   = (u16*)alloc(5120000, 2);
    u16* SPB   = (u16*)alloc(3211264, 2);
    u16* VAB   = (u16*)alloc(3211264, 2);
    u16* H2ALL = (u16*)alloc(3211264, 2);
    u16* H1A   = (u16*)alloc(65536, 2);
    u16* H1B   = (u16*)alloc(65536, 2);
    u16* H2BF  = (u16*)alloc(65536, 2);
    u16* STBF  = (u16*)alloc(65536, 2);
    u16* S2BF  = (u16*)alloc(65536, 2);
    u16* HTBF  = (u16*)alloc(65536, 2);
    u16* CHHBF = (u16*)alloc(65536, 2);
    u16* ATTBF = (u16*)alloc(65536, 2);
    float* M1  = (float*)alloc(65536, 4);
    float* M2  = (float*)alloc(65536, 4);
    float* HTF = (float*)alloc(65536, 4);
    float* HID = (float*)alloc(65536, 4);
    float* SEN = (float*)alloc(65536, 4);
    int*   BAR = (int*)alloc(2048, 4);

    // zero-init recurrent state + barrier counters (every call / replay)
    hipMemsetAsync(H1A, 0, 65536 * 2, stream);
    hipMemsetAsync(H2BF, 0, 65536 * 2, stream);
    hipMemsetAsync(M1, 0, 65536 * 4, stream);
    hipMemsetAsync(M2, 0, 65536 * 4, stream);
    hipMemsetAsync(BAR, 0, 2048 * 4, stream);

    // prep: conversions + packs + xw gather
    k_cvt8<<<38688, 256, 0, stream>>>(aff_s_w, aff_h_w, ws_w, wg_w, wv_w, wp_w, fc_w, SF,
                                      AFFS, AFFH, WSB, WGB, WVB, WPB, FCB, SPB);
    k_packX<<<(2621440 + 255) / 256, 256, 0, stream>>>(w_ih1, s_wx, W1X, WSX);
    k_packS<<<(5767168 + 255) / 256, 256, 0, stream>>>(w_ih1, w_hh1, s_wx, s_wh, w_ih2, w_hh2,
                                                       W1S, W2H, W2A);
    k_xw<<<(6422528 + 255) / 256, 256, 0, stream>>>(EMB, GIMG, CAP, XWB, 6422528);

    // batched precompute GEMMs
    k_p1ps<<<49 * 40, 256, 0, stream>>>(XWB, W1X, WSX, b_ih1, b_hh1, s_bx, s_bh, P1, PS);
    k_va<<<49 * 8, 256, 0, stream>>>(SPB, WVB, wv_b, VAB);

    // persistent sequential scan (64 co-resident blocks, fence-free barriers)
    k_scan<<<NBLK, 256, 0, stream>>>(W1S, W2H, W2A, AFFS, AFFH, WSB, WGB, WPB,
                                     P1, PS, VAB, SPB, b_ih2, b_hh2, aff_s_b, aff_h_b,
                                     wg_b, ws_b, wp_b, wh_w, wh_b,
                                     H1A, H1B, H2BF, STBF, S2BF, HTBF, CHHBF, ATTBF,
                                     M1, M2, HTF, HID, SEN, H2ALL, BAR);

    // final projection to vocab
    k_fc<<<49 * 157, 256, 0, stream>>>(H2ALL, FCB, fc_b, out);
}

// Round 6
// 18467.366 us; speedup vs baseline: 1.0088x; 1.0088x over previous
//
#include <hip/hip_runtime.h>

// ---------------------------------------------------------------------------
// Adaptive-attention LSTM decoder (B=128, P=49, D=E=A=512, V=10000, T=50).
//  * Persistent scan: 64 co-resident blocks, 6 phases/step, fence-free grid
//    barriers (atomic counter + vmcnt(0) drain of write-through stores).
//  * Coherence WITHOUT atomic loads: all inter-phase buffers ROTATE per step
//    (fresh addresses -> no stale cache lines anywhere); writers store
//    write-through (sc0 sc1); readers use normal cached loads.
//  * A-broadcast staging via async global_load_lds (16B), 32KB chunks,
//    double-buffered, counted vmcnt(8), source-swizzled (conflict-free reads).
//  * R=1 weight ownership (each weight byte read by exactly one block ->
//    L2-resident). LSTM cell states m1/m2 live in REGISTERS.
//  * Precompute: P1/Ps input-side gates, visual_att (bf16); final: fc GEMM.
// ---------------------------------------------------------------------------

typedef unsigned short u16;
typedef unsigned long long ull;
typedef short bf16x8 __attribute__((ext_vector_type(8)));
typedef float f32x4 __attribute__((ext_vector_type(4)));

#define MFMA16(a, b, c) __builtin_amdgcn_mfma_f32_16x16x32_bf16(a, b, c, 0, 0, 0)
#define NBLK 64

__device__ __forceinline__ u16 f2bf(float f) {
    union { float f; unsigned u; } v; v.f = f;
    return (u16)((v.u + 0x7fffu + ((v.u >> 16) & 1u)) >> 16);
}
__device__ __forceinline__ float bf2f(u16 h) {
    union { unsigned u; float f; } v; v.u = ((unsigned)h) << 16; return v.f;
}
__device__ __forceinline__ float sigm(float x) {
    x = fminf(fmaxf(x, -30.f), 30.f);
    return 1.f / (1.f + __expf(-x));
}
__device__ __forceinline__ float tanh_(float x) {
    x = fminf(fmaxf(x, -15.f), 15.f);
    float e = __expf(2.f * x);
    return (e - 1.f) / (e + 1.f);
}

// ---- write-through (reach LLC) stores; drained by vmcnt(0) at barrier ----
__device__ __forceinline__ void st16(u16* p, u16 v) {
    asm volatile("global_store_short %0, %1, off sc0 sc1" :: "v"(p), "v"((unsigned)v) : "memory");
}
__device__ __forceinline__ void st32f(float* p, float v) {
    asm volatile("global_store_dword %0, %1, off sc0 sc1" :: "v"(p), "v"(v) : "memory");
}
__device__ __forceinline__ void st64u(u16* p, ull v) {
    asm volatile("global_store_dwordx2 %0, %1, off sc0 sc1" :: "v"(p), "v"(v) : "memory");
}

// Fence-free grid barrier: drain own write-through stores, count arrivals.
__device__ __forceinline__ void grid_barrier(int* bar, int idx) {
    asm volatile("s_waitcnt vmcnt(0)" ::: "memory");
    __syncthreads();
    if (threadIdx.x == 0) {
        __hip_atomic_fetch_add(&bar[idx], 1, __ATOMIC_RELAXED, __HIP_MEMORY_SCOPE_AGENT);
        while (__hip_atomic_load(&bar[idx], __ATOMIC_RELAXED, __HIP_MEMORY_SCOPE_AGENT) < NBLK)
            __builtin_amdgcn_s_sleep(1);
    }
    __syncthreads();
    asm volatile("" ::: "memory");
}

// ---------------------------------------------------------------------------
// Column-parallel GEMM with async LDS staging.
// C[128 x NT*16] += A[128 x K] @ W[wrow0.., K]^T,  K = NCH*128.
// A = [A0 | A1] split at 512 (NCH==8) or single A0 (NCH==4); each matrix is
// [128][512] bf16 row-major. Staged in 32KB chunks (128 rows x 128 cols),
// double-buffered, via global_load_lds with SOURCE-side XOR swizzle so the
// MFMA-fragment ds_read_b128s are 2-way-conflict-free (free).
template<int NT, int NCH>
__device__ __forceinline__ void gemmX(const u16* A0, const u16* A1,
                                      const u16* __restrict__ W, int ldw, int wrow0,
                                      u16* lds, f32x4 acc[2][NT]) {
    const int tid = threadIdx.x;
    const int w = tid >> 6, lane = tid & 63, r = lane & 15, lg = lane >> 4;
    const int m_base = w * 32;
    const int lrow4 = lane >> 4;    // row-within-4-row group
    const int slot = lane & 15;     // 16B slot within row

    auto issue = [&](int c) {
        const u16* Ab = (NCH > 4 && c >= 4) ? A1 : A0;
        int cc = c & 3;
        u16* buf = lds + (c & 1) * 16384;
#pragma unroll
        for (int i = 0; i < 8; ++i) {
            int rbase = w * 32 + i * 4;
            int row = rbase + lrow4;
            int c16 = slot ^ (row & 7);             // source swizzle
            const u16* src = Ab + (size_t)row * 512 + cc * 128 + c16 * 8;
            u16* dst = buf + rbase * 128;           // wave-uniform; lane writes +lane*16B
            __builtin_amdgcn_global_load_lds(
                (const __attribute__((address_space(1))) void*)src,
                (__attribute__((address_space(3))) void*)dst, 16, 0, 0);
        }
    };
    auto compute = [&](int c) {
        const u16* buf = lds + (c & 1) * 16384;
#pragma unroll
        for (int k0 = 0; k0 < 128; k0 += 32) {
            int kk = k0 + lg * 8;
            int c16 = kk >> 3;
            int ra0 = m_base + r, ra1 = m_base + 16 + r;
            bf16x8 a0 = *(const bf16x8*)(buf + ra0 * 128 + ((c16 ^ (ra0 & 7)) << 3));
            bf16x8 a1 = *(const bf16x8*)(buf + ra1 * 128 + ((c16 ^ (ra1 & 7)) << 3));
#pragma unroll
            for (int j = 0; j < NT; ++j) {
                bf16x8 wf = *(const bf16x8*)(W + (size_t)(wrow0 + j * 16 + r) * ldw + c * 128 + kk);
                acc[0][j] = MFMA16(a0, wf, acc[0][j]);
                acc[1][j] = MFMA16(a1, wf, acc[1][j]);
            }
        }
    };

    issue(0);
#pragma unroll
    for (int c = 0; c < NCH; ++c) {
        if (c + 1 < NCH) {
            issue(c + 1);
            asm volatile("s_waitcnt vmcnt(8)" ::: "memory");  // chunk c landed; c+1 in flight
        } else {
            asm volatile("s_waitcnt vmcnt(0)" ::: "memory");
        }
        __builtin_amdgcn_sched_barrier(0);
        __syncthreads();
        compute(c);
        __syncthreads();
    }
}

// Plain-global-A gemm (pre/post kernels only).
__device__ __forceinline__ void gemm_2x4(const u16* __restrict__ A0, const u16* __restrict__ A1,
                                         int asplit, int lda0, int lda1,
                                         const u16* __restrict__ W, int ldw, int K,
                                         int m_base, int n_base, int nt, f32x4 acc[2][4]) {
    const int lane = threadIdx.x & 63, r = lane & 15, lg = lane >> 4;
    for (int k0 = 0; k0 < K; k0 += 32) {
        int kk = k0 + lg * 8;
        const u16* Ab; int ka, lda;
        if (k0 < asplit) { Ab = A0; ka = kk; lda = lda0; }
        else             { Ab = A1; ka = kk - asplit; lda = lda1; }
        bf16x8 a0 = *(const bf16x8*)(Ab + (size_t)(m_base + r) * lda + ka);
        bf16x8 a1 = *(const bf16x8*)(Ab + (size_t)(m_base + 16 + r) * lda + ka);
#pragma unroll
        for (int j = 0; j < 4; ++j) {
            if (j < nt) {
                bf16x8 wf = *(const bf16x8*)(W + (size_t)(n_base + j * 16 + r) * ldw + kk);
                acc[0][j] = MFMA16(a0, wf, acc[0][j]);
                acc[1][j] = MFMA16(a1, wf, acc[1][j]);
            }
        }
    }
}

// ---------------- one-time conversion / packing kernels ----------------

__global__ __launch_bounds__(256) void k_cvt8(
    const float* __restrict__ s0, const float* __restrict__ s1, const float* __restrict__ s2,
    const float* __restrict__ s3, const float* __restrict__ s4, const float* __restrict__ s5,
    const float* __restrict__ s6, const float* __restrict__ s7,
    u16* __restrict__ d0, u16* __restrict__ d1, u16* __restrict__ d2, u16* __restrict__ d3,
    u16* __restrict__ d4, u16* __restrict__ d5, u16* __restrict__ d6, u16* __restrict__ d7) {
    int i = blockIdx.x * 256 + threadIdx.x;
    const int S = 262144;
    if (i < 6 * S) {
        int seg = i >> 18, off = i & (S - 1);
        const float* s = seg == 0 ? s0 : seg == 1 ? s1 : seg == 2 ? s2 : seg == 3 ? s3 : seg == 4 ? s4 : s5;
        u16* d = seg == 0 ? d0 : seg == 1 ? d1 : seg == 2 ? d2 : seg == 3 ? d3 : seg == 4 ? d4 : d5;
        d[off] = f2bf(s[off]);
    } else if (i < 6 * S + 5120000) {
        int off = i - 6 * S;
        d6[off] = f2bf(s6[off]);
    } else {
        int off = i - 6 * S - 5120000;
        if (off < 3211264) d7[off] = f2bf(s7[off]);
    }
}

// input-side weight slices for the batched precompute
__global__ __launch_bounds__(256) void k_packX(const float* __restrict__ w_ih1,
                                               const float* __restrict__ s_wx,
                                               u16* __restrict__ W1X, u16* __restrict__ WSX) {
    int i = blockIdx.x * 256 + threadIdx.x;
    if (i < 2097152) {
        W1X[i] = f2bf(w_ih1[(size_t)(i >> 10) * 1536 + 512 + (i & 1023)]);
    } else if (i < 2621440) {
        int i2 = i - 2097152;
        WSX[i2] = f2bf(s_wx[(size_t)(i2 >> 10) * 1536 + 512 + (i2 & 1023)]);
    }
}

// Column-parallel scan weight layouts (colg = owning block's slice):
//  W1S [2560][1024]: row' = colg*160 + g*32 + dl (g in {i,f,g,o,sent}), d = colg*32+dl
//  W2H [2048][1024]: row' = colg*128 + g*32 + dl; K = [h1n | h2]
//  W2A [2048][ 512]: row' = colg*128 + g*32 + dl; K = att
__global__ __launch_bounds__(256) void k_packS(
    const float* __restrict__ w_ih1, const float* __restrict__ w_hh1,
    const float* __restrict__ s_wx, const float* __restrict__ s_wh,
    const float* __restrict__ w_ih2, const float* __restrict__ w_hh2,
    u16* __restrict__ W1S, u16* __restrict__ W2H, u16* __restrict__ W2A) {
    int i = blockIdx.x * 256 + threadIdx.x;
    if (i < 2621440) {
        int rp = i >> 10, k = i & 1023;
        int colg = rp / 160, rem = rp - colg * 160, g = rem >> 5, dl = rem & 31;
        int d = colg * 32 + dl;
        float v;
        if (g < 4) v = (k < 512) ? w_ih1[(size_t)(g * 512 + d) * 1536 + k]
                                 : w_hh1[(size_t)(g * 512 + d) * 512 + (k - 512)];
        else       v = (k < 512) ? s_wx[(size_t)d * 1536 + k]
                                 : s_wh[(size_t)d * 512 + (k - 512)];
        W1S[i] = f2bf(v);
    } else if (i < 2621440 + 2097152) {
        int i2 = i - 2621440;
        int rp = i2 >> 10, k = i2 & 1023;
        int colg = rp >> 7, rem = rp & 127, g = rem >> 5, dl = rem & 31;
        int d = colg * 32 + dl;
        float v = (k < 512) ? w_ih2[(size_t)(g * 512 + d) * 1024 + 512 + k]
                            : w_hh2[(size_t)(g * 512 + d) * 512 + (k - 512)];
        W2H[i2] = f2bf(v);
    } else if (i < 2621440 + 2097152 + 1048576) {
        int i3 = i - 2621440 - 2097152;
        int rp = i3 >> 9, k = i3 & 511;
        int colg = rp >> 7, rem = rp & 127, g = rem >> 5, dl = rem & 31;
        int d = colg * 32 + dl;
        W2A[i3] = f2bf(w_ih2[(size_t)(g * 512 + d) * 1024 + k]);
    }
}

// xw[t][b][k] : k<512 -> emb[cap[b][t]][k], else global_image[b][k-512]
__global__ __launch_bounds__(256) void k_xw(const float* __restrict__ emb, const float* __restrict__ gimg,
                                            const int* __restrict__ cap, u16* __restrict__ XW, int total) {
    int i = blockIdx.x * 256 + threadIdx.x;
    if (i >= total) return;
    int t = i >> 17;
    int rem = i & ((1 << 17) - 1);
    int b = rem >> 10, k = rem & 1023;
    float v = (k < 512) ? emb[(size_t)cap[b * 50 + t] * 512 + k] : gimg[b * 512 + (k - 512)];
    XW[i] = f2bf(v);
}

// ---------------- batched precompute GEMMs ----------------

__global__ __launch_bounds__(256) void k_p1ps(const u16* __restrict__ XW, const u16* __restrict__ W1X,
                                              const u16* __restrict__ WSX,
                                              const float* __restrict__ b_ih1, const float* __restrict__ b_hh1,
                                              const float* __restrict__ s_bx, const float* __restrict__ s_bh,
                                              float* __restrict__ P1, float* __restrict__ PS) {
    int bid = blockIdx.x;
    int ng = bid % 40, mg = bid / 40;
    int w = threadIdx.x >> 6, lane = threadIdx.x & 63, r = lane & 15, lg = lane >> 4;
    int m_base = mg * 128 + w * 32;
    f32x4 acc[2][4] = {};
    if (ng < 32) {
        int n_base = ng * 64;
        gemm_2x4(XW, XW, 1 << 28, 1024, 1024, W1X, 1024, 1024, m_base, n_base, 4, acc);
#pragma unroll
        for (int mt = 0; mt < 2; ++mt)
#pragma unroll
            for (int j = 0; j < 4; ++j)
#pragma unroll
                for (int reg = 0; reg < 4; ++reg) {
                    int row = m_base + mt * 16 + lg * 4 + reg;
                    int col = n_base + j * 16 + r;
                    P1[(size_t)row * 2048 + col] = acc[mt][j][reg] + b_ih1[col] + b_hh1[col];
                }
    } else {
        int n_base = (ng - 32) * 64;
        gemm_2x4(XW, XW, 1 << 28, 1024, 1024, WSX, 1024, 1024, m_base, n_base, 4, acc);
#pragma unroll
        for (int mt = 0; mt < 2; ++mt)
#pragma unroll
            for (int j = 0; j < 4; ++j)
#pragma unroll
                for (int reg = 0; reg < 4; ++reg) {
                    int row = m_base + mt * 16 + lg * 4 + reg;
                    int col = n_base + j * 16 + r;
                    PS[(size_t)row * 512 + col] = acc[mt][j][reg] + s_bx[col] + s_bh[col];
                }
    }
}

__global__ __launch_bounds__(256) void k_va(const u16* __restrict__ SPB, const u16* __restrict__ WVB,
                                            const float* __restrict__ wv_b, u16* __restrict__ VAB) {
    int bid = blockIdx.x;
    int ng = bid % 8, mg = bid / 8;
    int w = threadIdx.x >> 6, lane = threadIdx.x & 63, r = lane & 15, lg = lane >> 4;
    int m_base = mg * 128 + w * 32;
    int n_base = ng * 64;
    f32x4 acc[2][4] = {};
    gemm_2x4(SPB, SPB, 1 << 28, 512, 512, WVB, 512, 512, m_base, n_base, 4, acc);
#pragma unroll
    for (int mt = 0; mt < 2; ++mt)
#pragma unroll
        for (int j = 0; j < 4; ++j)
#pragma unroll
            for (int reg = 0; reg < 4; ++reg) {
                int row = m_base + mt * 16 + lg * 4 + reg;
                int col = n_base + j * 16 + r;
                VAB[(size_t)row * 512 + col] = f2bf(acc[mt][j][reg] + wv_b[col]);
            }
}

// ---------------- persistent scan ----------------

struct AttSm { float whwL[512]; float hidL[2][512]; float zbuf[2][64]; float albuf[2][64]; };

// PhD: adaptive attention; thread-halves handle batch rows bid and bid+64.
// All rotating inputs via NORMAL loads (fresh addresses).
__device__ __forceinline__ void p_attn(int bid, const u16* __restrict__ VAB, const float* SEN,
                                       const float* HID, const float* __restrict__ whw,
                                       const float* __restrict__ whb, const u16* __restrict__ SPB,
                                       const u16* S2, const float* HTF, u16* CHH, AttSm* A) {
    int tid = threadIdx.x;
    int half = tid >> 7, th = tid & 127;
    int b = bid + half * 64;
    for (int i = tid; i < 512; i += 256) A->whwL[i] = whw[i];
    for (int i = th; i < 512; i += 128) A->hidL[half][i] = HID[(size_t)b * 512 + i];
    __syncthreads();
    int w2 = th >> 6, lane = tid & 63;
    for (int p = w2; p < 50; p += 2) {
        float part = 0.f;
        if (p < 49) {
            const u16* src = VAB + ((size_t)b * 49 + p) * 512;
#pragma unroll
            for (int it = 0; it < 8; ++it) {
                int a = lane + it * 64;
                part += tanh_(bf2f(src[a]) + A->hidL[half][a]) * A->whwL[a];
            }
        } else {
#pragma unroll
            for (int it = 0; it < 8; ++it) {
                int a = lane + it * 64;
                part += tanh_(SEN[(size_t)b * 512 + a] + A->hidL[half][a]) * A->whwL[a];
            }
        }
#pragma unroll
        for (int o = 32; o; o >>= 1) part += __shfl_xor(part, o, 64);
        if (lane == 0) A->zbuf[half][p] = part + whb[0];
    }
    __syncthreads();
    if (th < 64) {
        float v = (lane < 50) ? A->zbuf[half][lane] : -1e30f;
        float mx = v;
#pragma unroll
        for (int o = 32; o; o >>= 1) mx = fmaxf(mx, __shfl_xor(mx, o, 64));
        float e = (lane < 50) ? __expf(v - mx) : 0.f;
        float s = e;
#pragma unroll
        for (int o = 32; o; o >>= 1) s += __shfl_xor(s, o, 64);
        if (lane < 50) A->albuf[half][lane] = e / s;
    }
    __syncthreads();
    float a49 = A->albuf[half][49];
    int d0 = th * 4;
    unsigned s2a = *(const unsigned*)(S2 + (size_t)b * 512 + d0);
    unsigned s2b = *(const unsigned*)(S2 + (size_t)b * 512 + d0 + 2);
    float acc0 = a49 * bf2f((u16)s2a), acc1 = a49 * bf2f((u16)(s2a >> 16));
    float acc2 = a49 * bf2f((u16)s2b), acc3 = a49 * bf2f((u16)(s2b >> 16));
    for (int p = 0; p < 49; ++p) {
        const u16* sf = SPB + ((size_t)b * 49 + p) * 512 + d0;
        unsigned q0 = *(const unsigned*)sf, q1 = *(const unsigned*)(sf + 2);
        float al = A->albuf[half][p];
        acc0 += al * bf2f((u16)q0); acc1 += al * bf2f((u16)(q0 >> 16));
        acc2 += al * bf2f((u16)q1); acc3 += al * bf2f((u16)(q1 >> 16));
    }
    acc0 += HTF[(size_t)b * 512 + d0];
    acc1 += HTF[(size_t)b * 512 + d0 + 1];
    acc2 += HTF[(size_t)b * 512 + d0 + 2];
    acc3 += HTF[(size_t)b * 512 + d0 + 3];
    ull pk = (ull)((unsigned)f2bf(acc0) | ((unsigned)f2bf(acc1) << 16))
           | ((ull)((unsigned)f2bf(acc2) | ((unsigned)f2bf(acc3) << 16)) << 32);
    st64u(CHH + (size_t)b * 512 + d0, pk);
    __syncthreads();
}

__global__ __launch_bounds__(256) void k_scan(
    const u16* __restrict__ W1S, const u16* __restrict__ W2H, const u16* __restrict__ W2A,
    const u16* __restrict__ AFFS, const u16* __restrict__ AFFH,
    const u16* __restrict__ WSB, const u16* __restrict__ WGB, const u16* __restrict__ WPB,
    const float* __restrict__ P1, const float* __restrict__ PS,
    const u16* __restrict__ VAB, const u16* __restrict__ SPB,
    const float* __restrict__ b_ih2, const float* __restrict__ b_hh2,
    const float* __restrict__ affs_b, const float* __restrict__ affh_b,
    const float* __restrict__ wg_b, const float* __restrict__ ws_b, const float* __restrict__ wp_b,
    const float* __restrict__ whw, const float* __restrict__ whb,
    u16* H1R, u16* H2R, u16* STR, u16* S2R, u16* HTBR, u16* CHHR, u16* ATTR,
    float* HTFR, float* SENR, float* HIDR, int* bar) {
    union SmemU {
        u16 stage[32768];   // 2 x 32KB staging buffers
        AttSm att;
    };
    __shared__ SmemU sm;
    u16* lds = sm.stage;
    const int bid = blockIdx.x;
    const int tid = threadIdx.x;
    const int w = tid >> 6, lane = tid & 63, r = lane & 15, lg = lane >> 4;

    float m1[16], m2[16];
#pragma unroll
    for (int i = 0; i < 16; ++i) { m1[i] = 0.f; m2[i] = 0.f; }

    int bi = 0;
    for (int t = 0; t < 49; ++t) {
        u16* H2c = H2R + (size_t)t * 65536;
        u16* H2n = H2R + (size_t)(t + 1) * 65536;
        u16* H1c = H1R + (size_t)t * 65536;
        u16* H1n = H1R + (size_t)(t + 1) * 65536;
        u16* STt = STR + (size_t)t * 65536;
        u16* S2t = S2R + (size_t)t * 65536;
        u16* HTBt = HTBR + (size_t)t * 65536;
        u16* CHHt = CHHR + (size_t)t * 65536;
        u16* ATTt = ATTR + (size_t)t * 65536;
        float* HTFt = HTFR + (size_t)t * 65536;
        float* SENt = SENR + (size_t)t * 65536;
        float* HIDt = HIDR + (size_t)t * 65536;

        // ---- PhA: LSTM1 + sentinel (blocks 0..15) ----
        if (bid < 16) {
            int colg = bid;
            f32x4 acc[2][10] = {};
            gemmX<10, 8>(H2c, H1c, W1S, 1024, colg * 160, lds, acc);
#pragma unroll
            for (int mt = 0; mt < 2; ++mt)
#pragma unroll
                for (int dh = 0; dh < 2; ++dh)
#pragma unroll
                    for (int reg = 0; reg < 4; ++reg) {
                        int row = w * 32 + mt * 16 + lg * 4 + reg;
                        int d = colg * 32 + dh * 16 + r;
                        const float* p1r = P1 + ((size_t)t * 128 + row) * 2048;
                        float gi = acc[mt][0 + dh][reg] + p1r[d];
                        float gf = acc[mt][2 + dh][reg] + p1r[512 + d];
                        float gg = acc[mt][4 + dh][reg] + p1r[1024 + d];
                        float go = acc[mt][6 + dh][reg] + p1r[1536 + d];
                        float gs = acc[mt][8 + dh][reg] + PS[((size_t)t * 128 + row) * 512 + d];
                        int mi = (mt * 2 + dh) * 4 + reg;
                        float m1n = sigm(gf) * m1[mi] + sigm(gi) * tanh_(gg);
                        m1[mi] = m1n;
                        float tm = tanh_(m1n);
                        st16(H1n + row * 512 + d, f2bf(sigm(go) * tm));
                        st16(STt + row * 512 + d, f2bf(sigm(gs) * tm));
                    }
        }
        grid_barrier(bar, bi++);

        // ---- PhB: g2p (16..31, regs), s2 (32..47), ht (48..63) ----
        f32x4 g2acc[2][8] = {};
        if (bid >= 16 && bid < 32) {
            gemmX<8, 8>(H1n, H2c, W2H, 1024, (bid - 16) * 128, lds, g2acc);
        } else if (bid >= 32 && bid < 48) {
            int colg = bid - 32;
            f32x4 acc[2][2] = {};
            gemmX<2, 4>(STt, STt, AFFS, 512, colg * 32, lds, acc);
#pragma unroll
            for (int mt = 0; mt < 2; ++mt)
#pragma unroll
                for (int j = 0; j < 2; ++j)
#pragma unroll
                    for (int reg = 0; reg < 4; ++reg) {
                        int row = w * 32 + mt * 16 + lg * 4 + reg;
                        int col = colg * 32 + j * 16 + r;
                        float v = fmaxf(acc[mt][j][reg] + affs_b[col], 0.f);
                        st16(S2t + row * 512 + col, f2bf(v));
                    }
        } else if (bid >= 48) {
            int colg = bid - 48;
            f32x4 acc[2][2] = {};
            gemmX<2, 4>(H1n, H1n, AFFH, 512, colg * 32, lds, acc);
#pragma unroll
            for (int mt = 0; mt < 2; ++mt)
#pragma unroll
                for (int j = 0; j < 2; ++j)
#pragma unroll
                    for (int reg = 0; reg < 4; ++reg) {
                        int row = w * 32 + mt * 16 + lg * 4 + reg;
                        int col = colg * 32 + j * 16 + r;
                        float v = tanh_(acc[mt][j][reg] + affh_b[col]);
                        st32f(HTFt + row * 512 + col, v);
                        st16(HTBt + row * 512 + col, f2bf(v));
                    }
        }
        grid_barrier(bar, bi++);

        // ---- PhC: sen (32..47), hid (48..63) ----
        if (bid >= 32 && bid < 48) {
            int colg = bid - 32;
            f32x4 acc[2][2] = {};
            gemmX<2, 4>(S2t, S2t, WSB, 512, colg * 32, lds, acc);
#pragma unroll
            for (int mt = 0; mt < 2; ++mt)
#pragma unroll
                for (int j = 0; j < 2; ++j)
#pragma unroll
                    for (int reg = 0; reg < 4; ++reg) {
                        int row = w * 32 + mt * 16 + lg * 4 + reg;
                        int col = colg * 32 + j * 16 + r;
                        st32f(SENt + row * 512 + col, acc[mt][j][reg] + ws_b[col]);
                    }
        } else if (bid >= 48) {
            int colg = bid - 48;
            f32x4 acc[2][2] = {};
            gemmX<2, 4>(HTBt, HTBt, WGB, 512, colg * 32, lds, acc);
#pragma unroll
            for (int mt = 0; mt < 2; ++mt)
#pragma unroll
                for (int j = 0; j < 2; ++j)
#pragma unroll
                    for (int reg = 0; reg < 4; ++reg) {
                        int row = w * 32 + mt * 16 + lg * 4 + reg;
                        int col = colg * 32 + j * 16 + r;
                        st32f(HIDt + row * 512 + col, acc[mt][j][reg] + wg_b[col]);
                    }
        }
        grid_barrier(bar, bi++);

        // ---- PhD: attention (all 64 blocks, 2 batch rows each) ----
        p_attn(bid, VAB, SENt, HIDt, whw, whb, SPB, S2t, HTFt, CHHt, &sm.att);
        grid_barrier(bar, bi++);

        // ---- PhE1: att_out = tanh(chh @ wp^T + b) (blocks 0..15) ----
        if (bid < 16) {
            int colg = bid;
            f32x4 acc[2][2] = {};
            gemmX<2, 4>(CHHt, CHHt, WPB, 512, colg * 32, lds, acc);
#pragma unroll
            for (int mt = 0; mt < 2; ++mt)
#pragma unroll
                for (int j = 0; j < 2; ++j)
#pragma unroll
                    for (int reg = 0; reg < 4; ++reg) {
                        int row = w * 32 + mt * 16 + lg * 4 + reg;
                        int col = colg * 32 + j * 16 + r;
                        st16(ATTt + row * 512 + col, f2bf(tanh_(acc[mt][j][reg] + wp_b[col])));
                    }
        }
        grid_barrier(bar, bi++);

        // ---- PhE2: LSTM2 (blocks 16..31, consumes register-parked g2acc) ----
        if (bid >= 16 && bid < 32) {
            int colg = bid - 16;
            gemmX<8, 4>(ATTt, ATTt, W2A, 512, colg * 128, lds, g2acc);
#pragma unroll
            for (int mt = 0; mt < 2; ++mt)
#pragma unroll
                for (int dh = 0; dh < 2; ++dh)
#pragma unroll
                    for (int reg = 0; reg < 4; ++reg) {
                        int row = w * 32 + mt * 16 + lg * 4 + reg;
                        int d = colg * 32 + dh * 16 + r;
                        float gi = g2acc[mt][0 + dh][reg] + b_ih2[d]        + b_hh2[d];
                        float gf = g2acc[mt][2 + dh][reg] + b_ih2[512 + d]  + b_hh2[512 + d];
                        float gg = g2acc[mt][4 + dh][reg] + b_ih2[1024 + d] + b_hh2[1024 + d];
                        float go = g2acc[mt][6 + dh][reg] + b_ih2[1536 + d] + b_hh2[1536 + d];
                        int mi = (mt * 2 + dh) * 4 + reg;
                        float m2n = sigm(gf) * m2[mi] + sigm(gi) * tanh_(gg);
                        m2[mi] = m2n;
                        st16(H2n + row * 512 + d, f2bf(sigm(go) * tanh_(m2n)));
                    }
        }
        if (t < 48) grid_barrier(bar, bi++);
    }
}

// Final: preds[b][t][v] = H2R[(t+1)*128+b] @ fc_w^T + fc_b
__global__ __launch_bounds__(256) void k_fc(const u16* __restrict__ H2, const u16* __restrict__ FCB,
                                            const float* __restrict__ fc_b, float* __restrict__ out) {
    int bid = blockIdx.x;
    int ng = bid % 157, mg = bid / 157;
    int w = threadIdx.x >> 6, lane = threadIdx.x & 63, r = lane & 15, lg = lane >> 4;
    int m_base = mg * 128 + w * 32;
    int n_base = ng * 64;
    int nt = (10000 - n_base) / 16; if (nt > 4) nt = 4;
    f32x4 acc[2][4] = {};
    gemm_2x4(H2, H2, 1 << 28, 512, 512, FCB, 512, 512, m_base, n_base, nt, acc);
#pragma unroll
    for (int mt = 0; mt < 2; ++mt)
#pragma unroll
        for (int j = 0; j < 4; ++j) {
            if (j < nt) {
#pragma unroll
                for (int reg = 0; reg < 4; ++reg) {
                    int row = m_base + mt * 16 + lg * 4 + reg;
                    int col = n_base + j * 16 + r;
                    int t = row >> 7, b = row & 127;
                    out[((size_t)b * 49 + t) * 10000 + col] = acc[mt][j][reg] + fc_b[col];
                }
            }
        }
}

// ---------------------------------------------------------------------------

extern "C" void kernel_launch(void* const* d_in, const int* in_sizes, int n_in,
                              void* d_out, int out_size, void* d_ws, size_t ws_size,
                              hipStream_t stream) {
    (void)in_sizes; (void)n_in; (void)out_size; (void)ws_size;

    const float* SF      = (const float*)d_in[0];
    const float* GIMG    = (const float*)d_in[1];
    const int*   CAP     = (const int*)d_in[2];
    const float* EMB     = (const float*)d_in[4];
    const float* w_ih1   = (const float*)d_in[5];
    const float* w_hh1   = (const float*)d_in[6];
    const float* b_ih1   = (const float*)d_in[7];
    const float* b_hh1   = (const float*)d_in[8];
    const float* s_wx    = (const float*)d_in[9];
    const float* s_bx    = (const float*)d_in[10];
    const float* s_wh    = (const float*)d_in[11];
    const float* s_bh    = (const float*)d_in[12];
    const float* w_ih2   = (const float*)d_in[13];
    const float* w_hh2   = (const float*)d_in[14];
    const float* b_ih2   = (const float*)d_in[15];
    const float* b_hh2   = (const float*)d_in[16];
    const float* aff_s_w = (const float*)d_in[17];
    const float* aff_s_b = (const float*)d_in[18];
    const float* aff_h_w = (const float*)d_in[19];
    const float* aff_h_b = (const float*)d_in[20];
    const float* ws_w    = (const float*)d_in[21];
    const float* ws_b    = (const float*)d_in[22];
    const float* wg_w    = (const float*)d_in[23];
    const float* wg_b    = (const float*)d_in[24];
    const float* wv_w    = (const float*)d_in[25];
    const float* wv_b    = (const float*)d_in[26];
    const float* wh_w    = (const float*)d_in[27];
    const float* wh_b    = (const float*)d_in[28];
    const float* wp_w    = (const float*)d_in[29];
    const float* wp_b    = (const float*)d_in[30];
    const float* fc_w    = (const float*)d_in[31];
    const float* fc_b    = (const float*)d_in[32];

    float* out = (float*)d_out;

    // fp32 scratch in d_out (fc overwrites all of d_out at the end):
    float* P1 = out;                       // 49*128*2048 floats
    float* PS = out + 12845056;            //  3,211,264 floats
    u16*  XWB = (u16*)(out + 17000000);    //  6,422,528 u16 (consumed before scan)
    // rotating per-step buffers (scan-only; fc overwrites later):
    u16*   H1R  = (u16*)(out + 21000000);  // 50*65536 u16
    u16*   STR  = (u16*)(out + 22700000);  // 49*65536 u16
    u16*   S2R  = (u16*)(out + 24400000);
    u16*   HTBR = (u16*)(out + 26100000);
    u16*   CHHR = (u16*)(out + 27800000);
    u16*   ATTR = (u16*)(out + 29500000);
    float* HTFR = out + 31200000;          // 49*65536 f32
    float* SENR = out + 34500000;
    float* HIDR = out + 37800000;          // ends ~41.0M < 62.72M

    char* ws = (char*)d_ws;
    size_t off = 0;
    auto alloc = [&](size_t elts, size_t esz) -> void* {
        void* p = ws + off;
        off += (elts * esz + 255) & ~(size_t)255;
        return p;
    };
    u16* W1S   = (u16*)alloc(2621440, 2);
    u16* W2H   = (u16*)alloc(2097152, 2);
    u16* W2A   = (u16*)alloc(1048576, 2);
    u16* W1X   = (u16*)alloc(2097152, 2);
    u16* WSX   = (u16*)alloc(524288, 2);
    u16* AFFS  = (u16*)alloc(262144, 2);
    u16* AFFH  = (u16*)alloc(262144, 2);
    u16* WSB   = (u16*)alloc(262144, 2);
    u16* WGB   = (u16*)alloc(262144, 2);
    u16* WVB   = (u16*)alloc(262144, 2);
    u16* WPB   = (u16*)alloc(262144, 2);
    u16* FCB   = (u16*)alloc(5120000, 2);
    u16* SPB   = (u16*)alloc(3211264, 2);
    u16* VAB   = (u16*)alloc(3211264, 2);
    u16* H2R   = (u16*)alloc(3276800, 2);  // 50*65536 u16 (read by k_fc)
    int* BAR   = (int*)alloc(2048, 4);

    // zero-init step-0 state + barrier counters (every call / replay)
    hipMemsetAsync(H1R, 0, 65536 * 2, stream);
    hipMemsetAsync(H2R, 0, 65536 * 2, stream);
    hipMemsetAsync(BAR, 0, 2048 * 4, stream);

    // prep: conversions + packs + xw gather
    k_cvt8<<<38688, 256, 0, stream>>>(aff_s_w, aff_h_w, ws_w, wg_w, wv_w, wp_w, fc_w, SF,
                                      AFFS, AFFH, WSB, WGB, WVB, WPB, FCB, SPB);
    k_packX<<<(2621440 + 255) / 256, 256, 0, stream>>>(w_ih1, s_wx, W1X, WSX);
    k_packS<<<(5767168 + 255) / 256, 256, 0, stream>>>(w_ih1, w_hh1, s_wx, s_wh, w_ih2, w_hh2,
                                                       W1S, W2H, W2A);
    k_xw<<<(6422528 + 255) / 256, 256, 0, stream>>>(EMB, GIMG, CAP, XWB, 6422528);

    // batched precompute GEMMs
    k_p1ps<<<49 * 40, 256, 0, stream>>>(XWB, W1X, WSX, b_ih1, b_hh1, s_bx, s_bh, P1, PS);
    k_va<<<49 * 8, 256, 0, stream>>>(SPB, WVB, wv_b, VAB);

    // persistent sequential scan (64 co-resident blocks, fence-free barriers)
    k_scan<<<NBLK, 256, 0, stream>>>(W1S, W2H, W2A, AFFS, AFFH, WSB, WGB, WPB,
                                     P1, PS, VAB, SPB, b_ih2, b_hh2, aff_s_b, aff_h_b,
                                     wg_b, ws_b, wp_b, wh_w, wh_b,
                                     H1R, H2R, STR, S2R, HTBR, CHHR, ATTR,
                                     HTFR, SENR, HIDR, BAR);

    // final projection to vocab
    k_fc<<<49 * 157, 256, 0, stream>>>(H2R + 65536, FCB, fc_b, out);
}